// Round 3
// baseline (4787.492 us; speedup 1.0000x reference)
//
#include <hip/hip_runtime.h>

#define NOBS 2048
#define NX   128
#define NY   64
#define BS   4            // scenarios per solver block
#define NT   512          // 8 waves/block -> 2-3 independent blocks per CU
#define NWAVE (NT / 64)   // 8
#define RPT  4            // obs rows per thread (NOBS / NT)
#define NITER 64

// ---- DPP wave reductions (VALU pipe, keeps LDS pipe free) ----
template <int CTRL>
__device__ __forceinline__ float dpp_f(float x) {
    return __int_as_float(__builtin_amdgcn_update_dpp(
        0, __float_as_int(x), CTRL, 0xf, 0xf, true));  // bound_ctrl: invalid lanes read 0
}
// After these, lane 63 holds the full-wave result.
__device__ __forceinline__ float wave_sum64(float v) {
    v += dpp_f<0x111>(v);   // row_shr:1
    v += dpp_f<0x112>(v);   // row_shr:2
    v += dpp_f<0x114>(v);   // row_shr:4
    v += dpp_f<0x118>(v);   // row_shr:8  -> lane 16r+15 = row sum
    v += dpp_f<0x142>(v);   // row_bcast15
    v += dpp_f<0x143>(v);   // row_bcast31 -> lane 63 = total
    return v;
}
__device__ __forceinline__ float wave_max64_nonneg(float v) {  // requires v >= 0 (0-fill safe)
    v = fmaxf(v, dpp_f<0x111>(v));
    v = fmaxf(v, dpp_f<0x112>(v));
    v = fmaxf(v, dpp_f<0x114>(v));
    v = fmaxf(v, dpp_f<0x118>(v));
    v = fmaxf(v, dpp_f<0x142>(v));
    v = fmaxf(v, dpp_f<0x143>(v));
    return v;
}

// ---- Kernel 1: Y_hat = X@W^T + b ; ep = Y - Y_hat ; epsum = sum(ep) ----
__global__ __launch_bounds__(256) void prep_kernel(
    const float* __restrict__ X, const float* __restrict__ Y,
    const float* __restrict__ W, const float* __restrict__ b,
    float* __restrict__ yhat_out, float* __restrict__ ep, float* __restrict__ epsum)
{
    __shared__ float Xs[4][NX];
    const int t = threadIdx.x;
    const int row0 = blockIdx.x * 4;
    for (int f = t; f < 4 * NX; f += 256)
        Xs[f >> 7][f & 127] = X[(row0 + (f >> 7)) * NX + (f & 127)];
    __syncthreads();

    const int k = t & 63;
    const int r = t >> 6;
    const float4* W4 = reinterpret_cast<const float4*>(W + k * NX);
    const float4* X4 = reinterpret_cast<const float4*>(&Xs[r][0]);
    float acc = 0.f;
    #pragma unroll
    for (int x = 0; x < NX / 4; ++x) {
        float4 wv = W4[x];
        float4 xv = X4[x];
        acc += wv.x * xv.x + wv.y * xv.y + wv.z * xv.z + wv.w * xv.w;
    }
    const float yh = acc + b[k];
    const int i = row0 + r;
    yhat_out[i * NY + k] = yh;
    const float e = Y[i * NY + k] - yh;
    ep[i * NY + k] = e;

    float se = wave_sum64(e);
    if ((t & 63) == 63) atomicAdd(epsum, se);
}

// ---- Kernel 2: batched projected-subgradient DRO solve ----
// 8-wave blocks, 6 barriers/iter, cross-wave reduces via broadcast-read.
__global__ __launch_bounds__(NT) void solve_kernel(
    const float* __restrict__ ep, const float* __restrict__ yhat,
    const float* __restrict__ epsum, const float* __restrict__ rho_p,
    float* __restrict__ zout)
{
    __shared__ float Zs[BS][NY];           // 1 KB  current z per scenario
    __shared__ float Yh[BS][NY];           // 1 KB
    __shared__ float V[NOBS][BS];          // 32 KB weighted residual v
    __shared__ float Rpart[NWAVE][NY][BS]; // 8 KB  per-wave partial r
    __shared__ float redM[NWAVE][BS];      // 128 B per-wave umax partials
    __shared__ float red2[NWAVE][4 * BS];  // 512 B per-wave sum partials
    __shared__ float cS[BS], lamS[BS], wAS[BS];

    const int t = threadIdx.x;
    const int lane = t & 63;
    const int wv = t >> 6;
    const int sc0 = blockIdx.x * BS;
    const float rho = rho_p[0];

    if (t < BS * NY) {
        const int j = t >> 6, k = t & 63;
        Yh[j][k] = yhat[(sc0 + j) * NY + k];
        Zs[j][k] = 1.0f / 64.0f;
    }
    if (t < BS) {
        cS[t] = epsum[0] * (1.0f / 131072.0f);  // mean(ep) == mean(ep @ z0)
        lamS[t] = 1.0f;
    }
    __syncthreads();

    const float4* ep4 = reinterpret_cast<const float4*>(ep);

    for (int it = 0; it < NITER; ++it) {
        const float lr = 0.05f / sqrtf((float)it + 1.0f);

        // ---- Phase A: s = ep.z - c for RPT rows x BS scenarios ----
        float s[RPT][BS];
        #pragma unroll
        for (int m = 0; m < RPT; ++m)
            #pragma unroll
            for (int j = 0; j < BS; ++j) s[m][j] = 0.f;

        #pragma unroll 4
        for (int k4 = 0; k4 < NY / 4; ++k4) {
            const float4 e0 = ep4[(t         ) * (NY / 4) + k4];
            const float4 e1 = ep4[(t +     NT) * (NY / 4) + k4];
            const float4 e2 = ep4[(t + 2 * NT) * (NY / 4) + k4];
            const float4 e3 = ep4[(t + 3 * NT) * (NY / 4) + k4];
            #pragma unroll
            for (int j = 0; j < BS; ++j) {
                const float4 zv = *reinterpret_cast<const float4*>(&Zs[j][k4 * 4]);
                s[0][j] += e0.x * zv.x + e0.y * zv.y + e0.z * zv.z + e0.w * zv.w;
                s[1][j] += e1.x * zv.x + e1.y * zv.y + e1.z * zv.z + e1.w * zv.w;
                s[2][j] += e2.x * zv.x + e2.y * zv.y + e2.z * zv.z + e2.w * zv.w;
                s[3][j] += e3.x * zv.x + e3.y * zv.y + e3.z * zv.z + e3.w * zv.w;
            }
        }
        float lamR[BS];
        #pragma unroll
        for (int j = 0; j < BS; ++j) {
            const float cj = cS[j];
            lamR[j] = lamS[j];
            #pragma unroll
            for (int m = 0; m < RPT; ++m) s[m][j] -= cj;
        }

        // ---- Phase B1: per-wave umax partials ----
        #pragma unroll
        for (int j = 0; j < BS; ++j) {
            float pm = fmaxf(fmaxf(s[0][j] * s[0][j], s[1][j] * s[1][j]),
                             fmaxf(s[2][j] * s[2][j], s[3][j] * s[3][j]));
            pm = wave_max64_nonneg(pm);
            if (lane == 63) redM[wv][j] = pm;
        }
        __syncthreads();   // bar 1

        // ---- Phase B2: every thread folds umax; wave-sum a/eq/a*s/eq*s ----
        float umaxR[BS];
        #pragma unroll
        for (int j = 0; j < BS; ++j) {
            float m_ = redM[0][j];
            #pragma unroll
            for (int w = 1; w < NWAVE; ++w) m_ = fmaxf(m_, redM[w][j]);
            umaxR[j] = m_;
        }
        #pragma unroll
        for (int j = 0; j < BS; ++j) {
            const float um = umaxR[j], lm = lamR[j];
            float pa = 0.f, pe = 0.f, pas = 0.f, pes = 0.f;
            #pragma unroll
            for (int m = 0; m < RPT; ++m) {
                const float ss = s[m][j], u = ss * ss;
                const float x = (u - um) + lm;
                const float a = (x > -lm) ? 1.0f : ((x == -lm) ? 0.5f : 0.0f);
                const float e = (u == um) ? 1.0f : 0.0f;
                pa += a; pe += e; pas += a * ss; pes += e * ss;
            }
            pa = wave_sum64(pa); pe = wave_sum64(pe);
            pas = wave_sum64(pas); pes = wave_sum64(pes);
            if (lane == 63) {
                red2[wv][j]          = pa;  red2[wv][BS + j]     = pe;
                red2[wv][2 * BS + j] = pas; red2[wv][3 * BS + j] = pes;
            }
        }
        __syncthreads();   // bar 2

        // ---- scalar stage: finalize sums, update c/lam, publish wA ----
        if (t < BS) {
            const int j = t;
            float sumA = 0.f, sumEq = 0.f, sumAS = 0.f, sumEqS = 0.f;
            #pragma unroll
            for (int w = 0; w < NWAVE; ++w) {
                sumA  += red2[w][j];          sumEq  += red2[w][BS + j];
                sumAS += red2[w][2 * BS + j]; sumEqS += red2[w][3 * BS + j];
            }
            const float abar = sumA * (1.0f / (float)NOBS);
            const float wA = (1.0f - abar) / sumEq;   // argmax weight / tie count
            wAS[j] = wA;
            const float gc = -2.0f * (sumAS * (1.0f / (float)NOBS) + wA * sumEqS);
            const float glam = (rho - 2.0f) + 2.0f * abar;
            cS[j] = cS[j] - lr * gc;
            lamS[j] = fmaxf(lamS[j] - lr * glam, 0.0f);
        }
        __syncthreads();   // bar 3

        // ---- Phase B4: v = (a/n + eq*wA) * s into LDS ----
        {
            float wAr[BS];
            #pragma unroll
            for (int j = 0; j < BS; ++j) wAr[j] = wAS[j];
            #pragma unroll
            for (int m = 0; m < RPT; ++m) {
                float vv[BS];
                #pragma unroll
                for (int j = 0; j < BS; ++j) {
                    const float ss = s[m][j], u = ss * ss;
                    const float x = (u - umaxR[j]) + lamR[j];
                    const float a = (x > -lamR[j]) ? 1.0f : ((x == -lamR[j]) ? 0.5f : 0.0f);
                    const float e = (u == umaxR[j]) ? 1.0f : 0.0f;
                    vv[j] = (a * (1.0f / (float)NOBS) + e * wAr[j]) * ss;
                }
                *reinterpret_cast<float4*>(&V[t + m * NT][0]) =
                    make_float4(vv[0], vv[1], vv[2], vv[3]);
            }
        }
        __syncthreads();   // bar 4

        // ---- Phase C: r = ep^T v (wave covers 256 obs; lane = column k) ----
        {
            float rp[BS];
            #pragma unroll
            for (int j = 0; j < BS; ++j) rp[j] = 0.f;
            const int ibeg = wv * (NOBS / NWAVE);
            #pragma unroll 4
            for (int ii = 0; ii < NOBS / NWAVE; ++ii) {
                const int i = ibeg + ii;
                const float e = ep[i * NY + lane];                             // coalesced
                const float4 va = *reinterpret_cast<const float4*>(&V[i][0]);  // broadcast
                rp[0] += e * va.x; rp[1] += e * va.y; rp[2] += e * va.z; rp[3] += e * va.w;
            }
            *reinterpret_cast<float4*>(&Rpart[wv][lane][0]) =
                make_float4(rp[0], rp[1], rp[2], rp[3]);
        }
        __syncthreads();   // bar 5

        // ---- Phase D: fold Rpart inline; update + simplex projection (wave j) ----
        if (wv < BS) {
            const int j = wv, k = lane;
            float r = 0.f;
            #pragma unroll
            for (int w = 0; w < NWAVE; ++w) r += Rpart[w][k][j];
            const float gz = 2.0f * r - Yh[j][k];
            const float vz = Zs[j][k] - lr * gz;

            // bitonic sort (descending) across 64 lanes
            float sv = vz;
            #pragma unroll
            for (int sz = 2; sz <= 64; sz <<= 1) {
                #pragma unroll
                for (int st = sz >> 1; st > 0; st >>= 1) {
                    const float other = __shfl_xor(sv, st, 64);
                    const bool desc = ((lane & sz) == 0);
                    const bool lower = ((lane & st) == 0);
                    const float mx = fmaxf(sv, other), mn = fminf(sv, other);
                    sv = (lower == desc) ? mx : mn;
                }
            }
            // inclusive scan -> cumsum - 1
            float css = sv;
            #pragma unroll
            for (int off = 1; off < 64; off <<= 1) {
                const float nb = __shfl_up(css, off, 64);
                if (lane >= off) css += nb;
            }
            css -= 1.0f;
            const bool cond = (sv - css / (float)(lane + 1)) > 0.0f;
            const unsigned long long bal = __ballot(cond);
            const int idx = __popcll(bal) - 1;
            const float cssIdx = __shfl(css, idx, 64);
            const float theta = cssIdx / (float)(idx + 1);
            Zs[j][k] = fmaxf(vz - theta, 0.0f);
        }
        __syncthreads();   // bar 6
    }

    if (t < BS * NY) {
        const int j = t >> 6, k = t & 63;
        zout[(sc0 + j) * NY + k] = Zs[j][k];
    }
}

extern "C" void kernel_launch(void* const* d_in, const int* in_sizes, int n_in,
                              void* d_out, int out_size, void* d_ws, size_t ws_size,
                              hipStream_t stream) {
    const float* X   = (const float*)d_in[0];
    const float* Y   = (const float*)d_in[1];
    const float* rho = (const float*)d_in[2];
    const float* W   = (const float*)d_in[3];
    const float* b   = (const float*)d_in[4];

    float* out   = (float*)d_out;
    float* zout  = out;                 // Z_star: 2048*64
    float* yhat  = out + NOBS * NY;     // Y_hat:  2048*64
    float* ep    = (float*)d_ws;        // 2048*64 f32 = 512 KB
    float* epsum = ep + NOBS * NY;      // 1 f32

    hipMemsetAsync(epsum, 0, sizeof(float), stream);
    prep_kernel<<<NOBS / 4, 256, 0, stream>>>(X, Y, W, b, yhat, ep, epsum);
    solve_kernel<<<NOBS / BS, NT, 0, stream>>>(ep, yhat, epsum, rho, zout);
}

// Round 4
// 2231.350 us; speedup vs baseline: 2.1456x; 2.1456x over previous
//
#include <hip/hip_runtime.h>

#define NOBS 2048
#define NX   128
#define NY   64
#define BS   8            // scenarios per solver block (R0 config: 256 blocks, 1/CU, all resident)
#define NT   1024         // 16 waves
#define NWAVE (NT / 64)
#define NITER 64

// ---- DPP wave reductions (VALU pipe, keeps LDS pipe free) ----
template <int CTRL>
__device__ __forceinline__ float dpp_f(float x) {
    return __int_as_float(__builtin_amdgcn_update_dpp(
        0, __float_as_int(x), CTRL, 0xf, 0xf, true));  // bound_ctrl: invalid lanes read 0
}
// After these, lane 63 holds the full-wave result.
__device__ __forceinline__ float wave_sum64(float v) {
    v += dpp_f<0x111>(v);   // row_shr:1
    v += dpp_f<0x112>(v);   // row_shr:2
    v += dpp_f<0x114>(v);   // row_shr:4
    v += dpp_f<0x118>(v);   // row_shr:8  -> lane 16r+15 = row sum
    v += dpp_f<0x142>(v);   // row_bcast15
    v += dpp_f<0x143>(v);   // row_bcast31 -> lane 63 = total
    return v;
}
__device__ __forceinline__ float wave_max64_nonneg(float v) {  // requires v >= 0 (0-fill safe)
    v = fmaxf(v, dpp_f<0x111>(v));
    v = fmaxf(v, dpp_f<0x112>(v));
    v = fmaxf(v, dpp_f<0x114>(v));
    v = fmaxf(v, dpp_f<0x118>(v));
    v = fmaxf(v, dpp_f<0x142>(v));
    v = fmaxf(v, dpp_f<0x143>(v));
    return v;
}

// ---- Kernel 1: Y_hat = X@W^T + b ; ep = Y - Y_hat ; epsum = sum(ep) ----
__global__ __launch_bounds__(256) void prep_kernel(
    const float* __restrict__ X, const float* __restrict__ Y,
    const float* __restrict__ W, const float* __restrict__ b,
    float* __restrict__ yhat_out, float* __restrict__ ep, float* __restrict__ epsum)
{
    __shared__ float Xs[4][NX];
    const int t = threadIdx.x;
    const int row0 = blockIdx.x * 4;
    for (int f = t; f < 4 * NX; f += 256)
        Xs[f >> 7][f & 127] = X[(row0 + (f >> 7)) * NX + (f & 127)];
    __syncthreads();

    const int k = t & 63;
    const int r = t >> 6;
    const float4* W4 = reinterpret_cast<const float4*>(W + k * NX);
    const float4* X4 = reinterpret_cast<const float4*>(&Xs[r][0]);
    float acc = 0.f;
    #pragma unroll
    for (int x = 0; x < NX / 4; ++x) {
        float4 wv = W4[x];
        float4 xv = X4[x];
        acc += wv.x * xv.x + wv.y * xv.y + wv.z * xv.z + wv.w * xv.w;
    }
    const float yh = acc + b[k];
    const int i = row0 + r;
    yhat_out[i * NY + k] = yh;
    const float e = Y[i * NY + k] - yh;
    ep[i * NY + k] = e;

    float se = wave_sum64(e);
    if ((t & 63) == 63) atomicAdd(epsum, se);
}

// ---- Kernel 2: batched projected-subgradient DRO solve ----
// R0 structure, restructured to 5 barriers/iter; all serial stages -> wave-parallel register work.
__global__ __launch_bounds__(NT, 4) void solve_kernel(
    const float* __restrict__ ep, const float* __restrict__ yhat,
    const float* __restrict__ epsum, const float* __restrict__ rho_p,
    float* __restrict__ zout)
{
    __shared__ float Zs[BS][NY];           // 2 KB  current z per scenario
    __shared__ float Yh[BS][NY];           // 2 KB
    __shared__ float V[NOBS][BS];          // 64 KB weighted residual v
    __shared__ float Rpart[NWAVE][NY][BS]; // 32 KB per-wave partial r
    __shared__ float redM[NWAVE][BS];      // 512 B per-wave umax partials
    __shared__ float red2[NWAVE][4 * BS];  // 2 KB  per-wave sum partials
    __shared__ float cS[BS], lamS[BS];

    const int t = threadIdx.x;
    const int lane = t & 63;
    const int wv = t >> 6;
    const int sc0 = blockIdx.x * BS;
    const float rho = rho_p[0];

    if (t < BS * NY) {
        const int j = t >> 6, k = t & 63;
        Yh[j][k] = yhat[(sc0 + j) * NY + k];
        Zs[j][k] = 1.0f / 64.0f;
    }
    if (t < BS) {
        cS[t] = epsum[0] * (1.0f / 131072.0f);  // mean(ep) == mean(ep @ z0)
        lamS[t] = 1.0f;
    }
    __syncthreads();

    const int i0 = t;          // each thread owns obs rows t and t+1024
    const int i1 = t + NT;
    const float4* ep4 = reinterpret_cast<const float4*>(ep);

    for (int it = 0; it < NITER; ++it) {
        const float lr = 0.05f / sqrtf((float)it + 1.0f);

        // ---- Phase A: s = ep.z - c for 2 rows x 8 scenarios (identical to R0) ----
        float s0[BS], s1[BS];
        #pragma unroll
        for (int j = 0; j < BS; ++j) { s0[j] = 0.f; s1[j] = 0.f; }
        #pragma unroll 4
        for (int k4 = 0; k4 < NY / 4; ++k4) {
            const float4 ea = ep4[i0 * (NY / 4) + k4];
            const float4 eb = ep4[i1 * (NY / 4) + k4];
            #pragma unroll
            for (int j = 0; j < BS; ++j) {
                const float4 zv = *reinterpret_cast<const float4*>(&Zs[j][k4 * 4]);
                s0[j] += ea.x * zv.x + ea.y * zv.y + ea.z * zv.z + ea.w * zv.w;
                s1[j] += eb.x * zv.x + eb.y * zv.y + eb.z * zv.z + eb.w * zv.w;
            }
        }
        float lamR[BS];
        #pragma unroll
        for (int j = 0; j < BS; ++j) {
            const float cj = cS[j];
            lamR[j] = lamS[j];
            s0[j] -= cj; s1[j] -= cj;
        }

        // ---- Phase B1: per-wave umax partials ----
        #pragma unroll
        for (int j = 0; j < BS; ++j) {
            float pm = fmaxf(s0[j] * s0[j], s1[j] * s1[j]);
            pm = wave_max64_nonneg(pm);
            if (lane == 63) redM[wv][j] = pm;
        }
        __syncthreads();   // bar 1

        // ---- umax fold: lanes 0..7 of EVERY wave fold 16 partials, shuffles broadcast ----
        float mv = 0.f;
        if (lane < BS) {
            #pragma unroll
            for (int w = 0; w < NWAVE; ++w) mv = fmaxf(mv, redM[w][lane]);
        }
        float umaxR[BS];
        #pragma unroll
        for (int j = 0; j < BS; ++j) umaxR[j] = __shfl(mv, j, 64);

        // ---- Phase B2: wave-sum a/eq/a*s/eq*s (JAX balanced-tie semantics) ----
        #pragma unroll
        for (int j = 0; j < BS; ++j) {
            const float um = umaxR[j], lm = lamR[j];
            float pa = 0.f, pe = 0.f, pas = 0.f, pes = 0.f;
            {
                const float s = s0[j], u = s * s;
                const float x = (u - um) + lm;
                const float a = (x > -lm) ? 1.0f : ((x == -lm) ? 0.5f : 0.0f);
                const float e = (u == um) ? 1.0f : 0.0f;
                pa += a; pe += e; pas += a * s; pes += e * s;
            }
            {
                const float s = s1[j], u = s * s;
                const float x = (u - um) + lm;
                const float a = (x > -lm) ? 1.0f : ((x == -lm) ? 0.5f : 0.0f);
                const float e = (u == um) ? 1.0f : 0.0f;
                pa += a; pe += e; pas += a * s; pes += e * s;
            }
            pa = wave_sum64(pa); pe = wave_sum64(pe);
            pas = wave_sum64(pas); pes = wave_sum64(pes);
            if (lane == 63) {
                red2[wv][j]          = pa;  red2[wv][BS + j]     = pe;
                red2[wv][2 * BS + j] = pas; red2[wv][3 * BS + j] = pes;
            }
        }
        __syncthreads();   // bar 2

        // ---- sum fold: lanes 0..31 fold red2; shuffles distribute; wA stays in regs ----
        float sv = 0.f;
        if (lane < 4 * BS) {
            #pragma unroll
            for (int w = 0; w < NWAVE; ++w) sv += red2[w][lane];
        }
        float wAr[BS], gcKeep = 0.f, glamKeep = 0.f;
        #pragma unroll
        for (int j = 0; j < BS; ++j) {
            const float sumA   = __shfl(sv, j, 64);
            const float sumEq  = __shfl(sv, BS + j, 64);
            const float sumAS  = __shfl(sv, 2 * BS + j, 64);
            const float sumEqS = __shfl(sv, 3 * BS + j, 64);
            const float abar = sumA * (1.0f / (float)NOBS);
            const float wA = (1.0f - abar) / sumEq;   // argmax weight / tie count
            wAr[j] = wA;
            if (lane == j) {
                gcKeep   = -2.0f * (sumAS * (1.0f / (float)NOBS) + wA * sumEqS);
                glamKeep = (rho - 2.0f) + 2.0f * abar;
            }
        }
        if (wv == 0 && lane < BS) {   // consumed next iteration (after bar 5)
            cS[lane]  = cS[lane] - lr * gcKeep;
            lamS[lane] = fmaxf(lamS[lane] - lr * glamKeep, 0.0f);
        }

        // ---- Phase B4: v = (a/n + eq*wA) * s into LDS ----
        {
            float v0[BS], v1[BS];
            #pragma unroll
            for (int j = 0; j < BS; ++j) {
                const float um = umaxR[j], lm = lamR[j], wA = wAr[j];
                {
                    const float s = s0[j], u = s * s;
                    const float x = (u - um) + lm;
                    const float a = (x > -lm) ? 1.0f : ((x == -lm) ? 0.5f : 0.0f);
                    const float e = (u == um) ? 1.0f : 0.0f;
                    v0[j] = (a * (1.0f / (float)NOBS) + e * wA) * s;
                }
                {
                    const float s = s1[j], u = s * s;
                    const float x = (u - um) + lm;
                    const float a = (x > -lm) ? 1.0f : ((x == -lm) ? 0.5f : 0.0f);
                    const float e = (u == um) ? 1.0f : 0.0f;
                    v1[j] = (a * (1.0f / (float)NOBS) + e * wA) * s;
                }
            }
            *reinterpret_cast<float4*>(&V[i0][0]) = make_float4(v0[0], v0[1], v0[2], v0[3]);
            *reinterpret_cast<float4*>(&V[i0][4]) = make_float4(v0[4], v0[5], v0[6], v0[7]);
            *reinterpret_cast<float4*>(&V[i1][0]) = make_float4(v1[0], v1[1], v1[2], v1[3]);
            *reinterpret_cast<float4*>(&V[i1][4]) = make_float4(v1[4], v1[5], v1[6], v1[7]);
        }
        __syncthreads();   // bar 3

        // ---- Phase C: r = ep^T v (wave covers 128 obs; lane = column k) ----
        {
            float rp[BS];
            #pragma unroll
            for (int j = 0; j < BS; ++j) rp[j] = 0.f;
            const int ibeg = wv * (NOBS / NWAVE);
            #pragma unroll 4
            for (int ii = 0; ii < NOBS / NWAVE; ++ii) {
                const int i = ibeg + ii;
                const float e = ep[i * NY + lane];                             // coalesced
                const float4 va = *reinterpret_cast<const float4*>(&V[i][0]);  // broadcast
                const float4 vb = *reinterpret_cast<const float4*>(&V[i][4]);  // broadcast
                rp[0] += e * va.x; rp[1] += e * va.y; rp[2] += e * va.z; rp[3] += e * va.w;
                rp[4] += e * vb.x; rp[5] += e * vb.y; rp[6] += e * vb.z; rp[7] += e * vb.w;
            }
            *reinterpret_cast<float4*>(&Rpart[wv][lane][0]) = make_float4(rp[0], rp[1], rp[2], rp[3]);
            *reinterpret_cast<float4*>(&Rpart[wv][lane][4]) = make_float4(rp[4], rp[5], rp[6], rp[7]);
        }
        __syncthreads();   // bar 4

        // ---- Phase D: fold Rpart inline; update + simplex projection (wave j) ----
        if (wv < BS) {
            const int j = wv, k = lane;
            float r = 0.f;
            #pragma unroll
            for (int w = 0; w < NWAVE; ++w) r += Rpart[w][k][j];
            const float gz = 2.0f * r - Yh[j][k];
            const float vz = Zs[j][k] - lr * gz;

            // bitonic sort (descending) across 64 lanes
            float sv2 = vz;
            #pragma unroll
            for (int sz = 2; sz <= 64; sz <<= 1) {
                #pragma unroll
                for (int st = sz >> 1; st > 0; st >>= 1) {
                    const float other = __shfl_xor(sv2, st, 64);
                    const bool desc = ((lane & sz) == 0);
                    const bool lower = ((lane & st) == 0);
                    const float mx = fmaxf(sv2, other), mn = fminf(sv2, other);
                    sv2 = (lower == desc) ? mx : mn;
                }
            }
            // inclusive scan -> cumsum - 1
            float css = sv2;
            #pragma unroll
            for (int off = 1; off < 64; off <<= 1) {
                const float nb = __shfl_up(css, off, 64);
                if (lane >= off) css += nb;
            }
            css -= 1.0f;
            const bool cond = (sv2 - css / (float)(lane + 1)) > 0.0f;
            const unsigned long long bal = __ballot(cond);
            const int idx = __popcll(bal) - 1;
            const float cssIdx = __shfl(css, idx, 64);
            const float theta = cssIdx / (float)(idx + 1);
            Zs[j][k] = fmaxf(vz - theta, 0.0f);
        }
        __syncthreads();   // bar 5
    }

    if (t < BS * NY) {
        const int j = t >> 6, k = t & 63;
        zout[(sc0 + j) * NY + k] = Zs[j][k];
    }
}

extern "C" void kernel_launch(void* const* d_in, const int* in_sizes, int n_in,
                              void* d_out, int out_size, void* d_ws, size_t ws_size,
                              hipStream_t stream) {
    const float* X   = (const float*)d_in[0];
    const float* Y   = (const float*)d_in[1];
    const float* rho = (const float*)d_in[2];
    const float* W   = (const float*)d_in[3];
    const float* b   = (const float*)d_in[4];

    float* out   = (float*)d_out;
    float* zout  = out;                 // Z_star: 2048*64
    float* yhat  = out + NOBS * NY;     // Y_hat:  2048*64
    float* ep    = (float*)d_ws;        // 2048*64 f32 = 512 KB
    float* epsum = ep + NOBS * NY;      // 1 f32

    hipMemsetAsync(epsum, 0, sizeof(float), stream);
    prep_kernel<<<NOBS / 4, 256, 0, stream>>>(X, Y, W, b, yhat, ep, epsum);
    solve_kernel<<<NOBS / BS, NT, 0, stream>>>(ep, yhat, epsum, rho, zout);
}

// Round 5
// 1891.766 us; speedup vs baseline: 2.5307x; 1.1795x over previous
//
#include <hip/hip_runtime.h>

#define NOBS 2048
#define NX   128
#define NY   64
#define BS   8            // scenarios per solver block (256 blocks, 1/CU, all resident)
#define NT   1024         // 16 waves
#define NWAVE (NT / 64)
#define NITER 64

typedef short short8 __attribute__((ext_vector_type(8)));   // 8 bf16 (4 VGPRs)
typedef float f32x4 __attribute__((ext_vector_type(4)));    // MFMA accumulator

// ---- bf16 split helpers (RNE) ----
__device__ __forceinline__ unsigned short bf16_rne(float x) {
    unsigned u = __float_as_uint(x);
    return (unsigned short)((u + 0x7FFFu + ((u >> 16) & 1u)) >> 16);
}
__device__ __forceinline__ float bf16_tof(unsigned short h) {
    return __uint_as_float(((unsigned)h) << 16);
}

// ---- DPP wave reductions (VALU pipe, keeps LDS pipe free) ----
template <int CTRL>
__device__ __forceinline__ float dpp_f(float x) {
    return __int_as_float(__builtin_amdgcn_update_dpp(
        0, __float_as_int(x), CTRL, 0xf, 0xf, true));  // bound_ctrl: invalid lanes read 0
}
__device__ __forceinline__ float wave_sum64(float v) {
    v += dpp_f<0x111>(v);
    v += dpp_f<0x112>(v);
    v += dpp_f<0x114>(v);
    v += dpp_f<0x118>(v);
    v += dpp_f<0x142>(v);
    v += dpp_f<0x143>(v);   // lane 63 = total
    return v;
}
__device__ __forceinline__ float wave_max64_nonneg(float v) {
    v = fmaxf(v, dpp_f<0x111>(v));
    v = fmaxf(v, dpp_f<0x112>(v));
    v = fmaxf(v, dpp_f<0x114>(v));
    v = fmaxf(v, dpp_f<0x118>(v));
    v = fmaxf(v, dpp_f<0x142>(v));
    v = fmaxf(v, dpp_f<0x143>(v));
    return v;
}

// ---- Kernel 1: Y_hat = X@W^T + b ; ep = Y - Y_hat ; epsum ; epT bf16 hi/lo frags ----
__global__ __launch_bounds__(256) void prep_kernel(
    const float* __restrict__ X, const float* __restrict__ Y,
    const float* __restrict__ W, const float* __restrict__ b,
    float* __restrict__ yhat_out, float* __restrict__ ep, float* __restrict__ epsum,
    unsigned short* __restrict__ epT_hi, unsigned short* __restrict__ epT_lo)
{
    __shared__ float Xs[4][NX];
    const int t = threadIdx.x;
    const int row0 = blockIdx.x * 4;
    for (int f = t; f < 4 * NX; f += 256)
        Xs[f >> 7][f & 127] = X[(row0 + (f >> 7)) * NX + (f & 127)];
    __syncthreads();

    const int k = t & 63;
    const int r = t >> 6;
    const float4* W4 = reinterpret_cast<const float4*>(W + k * NX);
    const float4* X4 = reinterpret_cast<const float4*>(&Xs[r][0]);
    float acc = 0.f;
    #pragma unroll
    for (int x = 0; x < NX / 4; ++x) {
        float4 wv = W4[x];
        float4 xv = X4[x];
        acc += wv.x * xv.x + wv.y * xv.y + wv.z * xv.z + wv.w * xv.w;
    }
    const float yh = acc + b[k];
    const int i = row0 + r;
    yhat_out[i * NY + k] = yh;
    const float e = Y[i * NY + k] - yh;
    ep[i * NY + k] = e;

    // bf16 hi/lo split of ep, scattered into v_mfma_f32_16x16x32_bf16 A-fragment
    // layout for epT (M = k-column of ep, K = i-row): element (m-tile, q-step, lane, d):
    //   A[row = lane&15][kk = 8*(lane>>4)+d]  ->  ep[i = 32q + 8*(lane>>4) + d][16m + (lane&15)]
    {
        const unsigned short hi = bf16_rne(e);
        const unsigned short lo = bf16_rne(e - bf16_tof(hi));
        const int m  = k >> 4;
        const int q  = i >> 5;
        const int lc = (k & 15) + 16 * ((i >> 3) & 3);
        const int d  = i & 7;
        const int idx = ((m * 64 + q) * 64 + lc) * 8 + d;
        epT_hi[idx] = hi;
        epT_lo[idx] = lo;
    }

    float se = wave_sum64(e);
    if ((t & 63) == 63) atomicAdd(epsum, se);
}

// ---- Kernel 2: batched projected-subgradient DRO solve ----
// Phases A/B on VALU (per-thread row ownership), Phase C on matrix cores
// (bf16 hi/lo 3-term split), 5 barriers/iter.
__global__ __launch_bounds__(NT, 4) void solve_kernel(
    const float* __restrict__ ep, const float* __restrict__ yhat,
    const float* __restrict__ epsum, const float* __restrict__ rho_p,
    const unsigned short* __restrict__ epT_hi, const unsigned short* __restrict__ epT_lo,
    float* __restrict__ zout)
{
    __shared__ float Zs[BS][NY];                 // 2 KB
    __shared__ float Yh[BS][NY];                 // 2 KB
    __shared__ unsigned short VT_hi[BS][2056];   // 32.1 KB  v hi (row-padded: 16B align + bank spread)
    __shared__ unsigned short VT_lo[BS][2056];   // 32.1 KB  v lo
    __shared__ float Rp2[4][4][64][4];           // 16 KB    [g][m][lane][reg] MFMA partials
    __shared__ float redM[NWAVE][BS];            // per-wave umax partials
    __shared__ float red2[NWAVE][4 * BS];        // per-wave sum partials
    __shared__ float cS[BS], lamS[BS];
    __shared__ __align__(16) unsigned short zb[8];  // zero B-frag for cols >= BS

    const int t = threadIdx.x;
    const int lane = t & 63;
    const int wv = t >> 6;
    const int sc0 = blockIdx.x * BS;
    const float rho = rho_p[0];

    if (t < BS * NY) {
        const int j = t >> 6, k = t & 63;
        Yh[j][k] = yhat[(sc0 + j) * NY + k];
        Zs[j][k] = 1.0f / 64.0f;
    }
    if (t < BS) {
        cS[t] = epsum[0] * (1.0f / 131072.0f);  // mean(ep) == mean(ep @ z0)
        lamS[t] = 1.0f;
    }
    if (t < 8) zb[t] = 0;
    __syncthreads();

    const int i0 = t;          // each thread owns obs rows t and t+1024
    const int i1 = t + NT;
    const float4* ep4 = reinterpret_cast<const float4*>(ep);

    for (int it = 0; it < NITER; ++it) {
        const float lr = 0.05f / sqrtf((float)it + 1.0f);

        // ---- Phase A: s = ep.z - c for 2 rows x 8 scenarios (fp32 VALU) ----
        float s0[BS], s1[BS];
        #pragma unroll
        for (int j = 0; j < BS; ++j) { s0[j] = 0.f; s1[j] = 0.f; }
        #pragma unroll 4
        for (int k4 = 0; k4 < NY / 4; ++k4) {
            const float4 ea = ep4[i0 * (NY / 4) + k4];
            const float4 eb = ep4[i1 * (NY / 4) + k4];
            #pragma unroll
            for (int j = 0; j < BS; ++j) {
                const float4 zv = *reinterpret_cast<const float4*>(&Zs[j][k4 * 4]);
                s0[j] += ea.x * zv.x + ea.y * zv.y + ea.z * zv.z + ea.w * zv.w;
                s1[j] += eb.x * zv.x + eb.y * zv.y + eb.z * zv.z + eb.w * zv.w;
            }
        }
        float lamR[BS];
        #pragma unroll
        for (int j = 0; j < BS; ++j) {
            const float cj = cS[j];
            lamR[j] = lamS[j];
            s0[j] -= cj; s1[j] -= cj;
        }

        // ---- Phase B1: per-wave umax partials ----
        #pragma unroll
        for (int j = 0; j < BS; ++j) {
            float pm = fmaxf(s0[j] * s0[j], s1[j] * s1[j]);
            pm = wave_max64_nonneg(pm);
            if (lane == 63) redM[wv][j] = pm;
        }
        __syncthreads();   // bar 1

        // ---- umax fold: lanes 0..7 of every wave fold, shuffles broadcast ----
        float mv = 0.f;
        if (lane < BS) {
            #pragma unroll
            for (int w = 0; w < NWAVE; ++w) mv = fmaxf(mv, redM[w][lane]);
        }
        float umaxR[BS];
        #pragma unroll
        for (int j = 0; j < BS; ++j) umaxR[j] = __shfl(mv, j, 64);

        // ---- Phase B2: wave-sum a/eq/a*s/eq*s (JAX balanced-tie semantics) ----
        #pragma unroll
        for (int j = 0; j < BS; ++j) {
            const float um = umaxR[j], lm = lamR[j];
            float pa = 0.f, pe = 0.f, pas = 0.f, pes = 0.f;
            {
                const float s = s0[j], u = s * s;
                const float x = (u - um) + lm;
                const float a = (x > -lm) ? 1.0f : ((x == -lm) ? 0.5f : 0.0f);
                const float e = (u == um) ? 1.0f : 0.0f;
                pa += a; pe += e; pas += a * s; pes += e * s;
            }
            {
                const float s = s1[j], u = s * s;
                const float x = (u - um) + lm;
                const float a = (x > -lm) ? 1.0f : ((x == -lm) ? 0.5f : 0.0f);
                const float e = (u == um) ? 1.0f : 0.0f;
                pa += a; pe += e; pas += a * s; pes += e * s;
            }
            pa = wave_sum64(pa); pe = wave_sum64(pe);
            pas = wave_sum64(pas); pes = wave_sum64(pes);
            if (lane == 63) {
                red2[wv][j]          = pa;  red2[wv][BS + j]     = pe;
                red2[wv][2 * BS + j] = pas; red2[wv][3 * BS + j] = pes;
            }
        }
        __syncthreads();   // bar 2

        // ---- sum fold: lanes 0..31 fold red2; shuffles distribute; wA in regs ----
        float sv = 0.f;
        if (lane < 4 * BS) {
            #pragma unroll
            for (int w = 0; w < NWAVE; ++w) sv += red2[w][lane];
        }
        float wAr[BS], gcKeep = 0.f, glamKeep = 0.f;
        #pragma unroll
        for (int j = 0; j < BS; ++j) {
            const float sumA   = __shfl(sv, j, 64);
            const float sumEq  = __shfl(sv, BS + j, 64);
            const float sumAS  = __shfl(sv, 2 * BS + j, 64);
            const float sumEqS = __shfl(sv, 3 * BS + j, 64);
            const float abar = sumA * (1.0f / (float)NOBS);
            const float wA = (1.0f - abar) / sumEq;   // argmax weight / tie count
            wAr[j] = wA;
            if (lane == j) {
                gcKeep   = -2.0f * (sumAS * (1.0f / (float)NOBS) + wA * sumEqS);
                glamKeep = (rho - 2.0f) + 2.0f * abar;
            }
        }
        if (wv == 0 && lane < BS) {   // consumed next iteration (after bar 5)
            cS[lane]  = cS[lane] - lr * gcKeep;
            lamS[lane] = fmaxf(lamS[lane] - lr * glamKeep, 0.0f);
        }

        // ---- Phase B4: v = (a/n + eq*wA) * s -> bf16 hi/lo into VT (B-frag feed) ----
        #pragma unroll
        for (int j = 0; j < BS; ++j) {
            const float um = umaxR[j], lm = lamR[j], wA = wAr[j];
            float v0j, v1j;
            {
                const float s = s0[j], u = s * s;
                const float x = (u - um) + lm;
                const float a = (x > -lm) ? 1.0f : ((x == -lm) ? 0.5f : 0.0f);
                const float e = (u == um) ? 1.0f : 0.0f;
                v0j = (a * (1.0f / (float)NOBS) + e * wA) * s;
            }
            {
                const float s = s1[j], u = s * s;
                const float x = (u - um) + lm;
                const float a = (x > -lm) ? 1.0f : ((x == -lm) ? 0.5f : 0.0f);
                const float e = (u == um) ? 1.0f : 0.0f;
                v1j = (a * (1.0f / (float)NOBS) + e * wA) * s;
            }
            const unsigned short h0 = bf16_rne(v0j);
            VT_hi[j][i0] = h0;
            VT_lo[j][i0] = bf16_rne(v0j - bf16_tof(h0));
            const unsigned short h1 = bf16_rne(v1j);
            VT_hi[j][i1] = h1;
            VT_lo[j][i1] = bf16_rne(v1j - bf16_tof(h1));
        }
        __syncthreads();   // bar 3

        // ---- Phase C: r = ep^T v via MFMA, 3-term bf16 split ----
        // wave wv: m-tile = wv&3 (16 k-cols), group g = wv>>2 (16 of 64 i-steps)
        {
            const int m = wv & 3;
            const int g = wv >> 2;
            const int jb = lane & 15;       // B-frag column (scenario)
            const int h  = lane >> 4;       // k-chunk within frag
            const bool jvalid = (jb < BS);
            f32x4 acc = {0.f, 0.f, 0.f, 0.f};
            #pragma unroll 4
            for (int qq = 0; qq < 16; ++qq) {
                const int q = g * 16 + qq;
                const int aoff = ((m * 64 + q) * 64 + lane) * 8;
                const short8 ah = *(const short8*)(epT_hi + aoff);
                const short8 al = *(const short8*)(epT_lo + aoff);
                const unsigned short* vh = jvalid ? &VT_hi[jb][(q << 5) + (h << 3)] : zb;
                const unsigned short* vl = jvalid ? &VT_lo[jb][(q << 5) + (h << 3)] : zb;
                const short8 bh = *(const short8*)vh;
                const short8 bl = *(const short8*)vl;
                acc = __builtin_amdgcn_mfma_f32_16x16x32_bf16(al, bh, acc, 0, 0, 0);
                acc = __builtin_amdgcn_mfma_f32_16x16x32_bf16(ah, bl, acc, 0, 0, 0);
                acc = __builtin_amdgcn_mfma_f32_16x16x32_bf16(ah, bh, acc, 0, 0, 0);
            }
            *(f32x4*)(&Rp2[g][m][lane][0]) = acc;   // stride-16B/lane: conflict-free
        }
        __syncthreads();   // bar 4

        // ---- Phase D: fold Rp2 (4 groups); update + simplex projection (wave j) ----
        if (wv < BS) {
            const int j = wv, k = lane;
            // D-frag: value r[16m + 4*(ll>>4) + reg][ll&15] at lane ll, reg
            const int m = k >> 4, p = k & 3, ll = ((k >> 2) & 3) * 16 + j;
            const float r = Rp2[0][m][ll][p] + Rp2[1][m][ll][p]
                          + Rp2[2][m][ll][p] + Rp2[3][m][ll][p];
            const float gz = 2.0f * r - Yh[j][k];
            const float vz = Zs[j][k] - lr * gz;

            // bitonic sort (descending) across 64 lanes
            float sv2 = vz;
            #pragma unroll
            for (int sz = 2; sz <= 64; sz <<= 1) {
                #pragma unroll
                for (int st = sz >> 1; st > 0; st >>= 1) {
                    const float other = __shfl_xor(sv2, st, 64);
                    const bool desc = ((lane & sz) == 0);
                    const bool lower = ((lane & st) == 0);
                    const float mx = fmaxf(sv2, other), mn = fminf(sv2, other);
                    sv2 = (lower == desc) ? mx : mn;
                }
            }
            // inclusive scan -> cumsum - 1
            float css = sv2;
            #pragma unroll
            for (int off = 1; off < 64; off <<= 1) {
                const float nb = __shfl_up(css, off, 64);
                if (lane >= off) css += nb;
            }
            css -= 1.0f;
            const bool cond = (sv2 - css / (float)(lane + 1)) > 0.0f;
            const unsigned long long bal = __ballot(cond);
            const int idx = __popcll(bal) - 1;
            const float cssIdx = __shfl(css, idx, 64);
            const float theta = cssIdx / (float)(idx + 1);
            Zs[j][k] = fmaxf(vz - theta, 0.0f);
        }
        __syncthreads();   // bar 5
    }

    if (t < BS * NY) {
        const int j = t >> 6, k = t & 63;
        zout[(sc0 + j) * NY + k] = Zs[j][k];
    }
}

extern "C" void kernel_launch(void* const* d_in, const int* in_sizes, int n_in,
                              void* d_out, int out_size, void* d_ws, size_t ws_size,
                              hipStream_t stream) {
    const float* X   = (const float*)d_in[0];
    const float* Y   = (const float*)d_in[1];
    const float* rho = (const float*)d_in[2];
    const float* W   = (const float*)d_in[3];
    const float* b   = (const float*)d_in[4];

    float* out   = (float*)d_out;
    float* zout  = out;                 // Z_star: 2048*64
    float* yhat  = out + NOBS * NY;     // Y_hat:  2048*64

    // workspace: epT_hi | epT_lo | ep fp32 | epsum  (16B-aligned segments first)
    unsigned short* epT_hi = (unsigned short*)d_ws;              // 64*2048 bf16 = 256 KB
    unsigned short* epT_lo = epT_hi + NY * NOBS;                 // 256 KB
    float* ep    = (float*)(epT_lo + NY * NOBS);                 // 512 KB
    float* epsum = ep + NOBS * NY;                               // 1 f32

    hipMemsetAsync(epsum, 0, sizeof(float), stream);
    prep_kernel<<<NOBS / 4, 256, 0, stream>>>(X, Y, W, b, yhat, ep, epsum, epT_hi, epT_lo);
    solve_kernel<<<NOBS / BS, NT, 0, stream>>>(ep, yhat, epsum, rho, epT_hi, epT_lo, zout);
}